// Round 13
// baseline (428.822 us; speedup 1.0000x reference)
//
#include <hip/hip_runtime.h>
#include <hip/hip_bf16.h>
#include <math.h>
#include <float.h>

#define B_    32
#define C_    1536
#define T_    2000
#define TP_   2048  // padded T for xt
#define BOT_  128
#define EPS_  1e-4f

#define CH    64    // c-chunk, phase 1
#define TC    32    // t-chunk per block
#define NTS   64    // 2048/32

typedef __attribute__((ext_vector_type(8))) short short8;
typedef __attribute__((ext_vector_type(4))) short short4v;
typedef __attribute__((ext_vector_type(4))) float f32x4;

static __device__ __forceinline__ unsigned short f2bf(float f) {
    unsigned u = __float_as_uint(f);
    u += 0x7FFFu + ((u >> 16) & 1u);           // RTNE
    return (unsigned short)(u >> 16);
}
static __device__ __forceinline__ float bf2f(unsigned short u) {
    return __uint_as_float(((unsigned)u) << 16);
}

// ---------------------------------------------------------------------------
// K1: per-(b,c) mean/std over T (fp32 exact) AND bf16 transpose
//     xt[b][t][c] (t padded to 2048 with zeros).
// ---------------------------------------------------------------------------
__global__ __launch_bounds__(256) void stats_transpose(
    const float* __restrict__ x, float* __restrict__ mean_s, float* __restrict__ std_s,
    unsigned short* __restrict__ xt) {
    const int b = blockIdx.y, cb0 = blockIdx.x * 64;
    const int tid = threadIdx.x, lane = tid & 63, w = tid >> 6;
    const int c0 = (lane & 15) * 4, tb = lane >> 4;

    const float* xb = x + ((size_t)b * C_ + cb0) * T_;
    unsigned short* xo = xt + (size_t)b * TP_ * C_ + cb0;

    float s1[4] = {0.f, 0.f, 0.f, 0.f}, s2[4] = {0.f, 0.f, 0.f, 0.f};

    for (int it = 0; it < TP_ / 64; ++it) {
        const int tbase = it * 64 + w * 16 + tb * 4;
        f32x4 v[4];
        if (tbase < T_) {   // tbase%4==0 and T%4==0 -> full float4 valid
            #pragma unroll
            for (int k = 0; k < 4; ++k)
                v[k] = *reinterpret_cast<const f32x4*>(xb + (size_t)(c0 + k) * T_ + tbase);
        } else {
            #pragma unroll
            for (int k = 0; k < 4; ++k)
                v[k] = (f32x4){0.f, 0.f, 0.f, 0.f};
        }
        #pragma unroll
        for (int k = 0; k < 4; ++k) {
            s1[k] += (v[k][0] + v[k][1]) + (v[k][2] + v[k][3]);
            s2[k] = fmaf(v[k][0], v[k][0], fmaf(v[k][1], v[k][1],
                    fmaf(v[k][2], v[k][2], fmaf(v[k][3], v[k][3], s2[k]))));
        }
        #pragma unroll
        for (int j = 0; j < 4; ++j) {
            short4v pk;
            pk[0] = (short)f2bf(v[0][j]);
            pk[1] = (short)f2bf(v[1][j]);
            pk[2] = (short)f2bf(v[2][j]);
            pk[3] = (short)f2bf(v[3][j]);
            *reinterpret_cast<short4v*>(xo + (size_t)(tbase + j) * C_ + c0) = pk;
        }
    }

    #pragma unroll
    for (int k = 0; k < 4; ++k) {
        s1[k] += __shfl_xor(s1[k], 16); s1[k] += __shfl_xor(s1[k], 32);
        s2[k] += __shfl_xor(s2[k], 16); s2[k] += __shfl_xor(s2[k], 32);
    }
    __shared__ float sb[4][64][2];
    if (lane < 16) {
        #pragma unroll
        for (int k = 0; k < 4; ++k) {
            sb[w][c0 + k][0] = s1[k];
            sb[w][c0 + k][1] = s2[k];
        }
    }
    __syncthreads();
    if (tid < 64) {
        float S1 = sb[0][tid][0] + sb[1][tid][0] + sb[2][tid][0] + sb[3][tid][0];
        float S2 = sb[0][tid][1] + sb[1][tid][1] + sb[2][tid][1] + sb[3][tid][1];
        float mean = S1 / (float)T_;
        float var  = (S2 - S1 * mean) / (float)(T_ - 1);
        mean_s[(size_t)b * C_ + cb0 + tid] = mean;
        std_s[(size_t)b * C_ + cb0 + tid]  = sqrtf(fmaxf(var, EPS_));
    }
}

// ---------------------------------------------------------------------------
// K1b: convert W1[:, :C] and W2 to bf16.
// ---------------------------------------------------------------------------
__global__ __launch_bounds__(256) void cvt_kernel(
    const float* __restrict__ W1, const float* __restrict__ W2,
    unsigned short* __restrict__ W1b, unsigned short* __restrict__ W2b) {
    int idx = blockIdx.x * 256 + threadIdx.x;
    if (idx < BOT_ * C_) {
        int o = idx / C_, c = idx - o * C_;
        W1b[idx] = f2bf(W1[(size_t)o * (3 * C_) + c]);
        W2b[idx] = f2bf(W2[idx]);
    }
}

// ---------------------------------------------------------------------------
// K2: cb[b][o] = b1[o] + sum_c W1[o][C+c]*mean[b][c] + W1[o][2C+c]*std[b][c]
// ---------------------------------------------------------------------------
__global__ __launch_bounds__(128) void cb_kernel(
    const float* __restrict__ W1, const float* __restrict__ b1,
    const float* __restrict__ mean_s, const float* __restrict__ std_s,
    float* __restrict__ cb) {
    __shared__ float ml[C_];
    __shared__ float sl[C_];
    const int b = blockIdx.x;
    for (int c = threadIdx.x; c < C_; c += 128) {
        ml[c] = mean_s[(size_t)b * C_ + c];
        sl[c] = std_s[(size_t)b * C_ + c];
    }
    __syncthreads();
    const int o = threadIdx.x;
    const float* wm = W1 + (size_t)o * (3 * C_) + C_;
    const float* ws = wm + C_;
    float am0 = 0.f, am1 = 0.f, as0 = 0.f, as1 = 0.f;
    for (int c = 0; c < C_; c += 2) {
        am0 = fmaf(wm[c],     ml[c],     am0);
        am1 = fmaf(wm[c + 1], ml[c + 1], am1);
        as0 = fmaf(ws[c],     sl[c],     as0);
        as1 = fmaf(ws[c + 1], sl[c + 1], as1);
    }
    cb[(size_t)b * BOT_ + o] = b1[o] + (am0 + am1) + (as0 + as1);
}

// ---------------------------------------------------------------------------
// K3 (fused, TC=32, occupancy-first): per (b, 32-t chunk), 4 waves, 8KB LDS.
//  phase 1: 24 chunks of 64 c. Xb (32t x 64c) staged (1 short8/thread,
//    reg-prefetched); wave w owns o-block [w*32,+32); 8 MFMA/chunk/wave.
//  epilogue: +cb, relu -> Hl[32t][128o] bf16 (union over Xb).
//  phase 2: 24 c-iters of 64; swapped MFMA (A = Hl t-rows, B = W2 c-rows),
//    lane=c, regs=t; max-free exp (|L|<~3, b2 cancels); x from xt bf16
//    (coalesced in c, L2-hot); 2-shfl reduce; partials to ws.
// Grid (64, 32) = 2048 blocks -> 8 blocks/CU target.
// ---------------------------------------------------------------------------
__global__ __launch_bounds__(256) void fused_main(
    const unsigned short* __restrict__ xt,
    const unsigned short* __restrict__ W1b, const unsigned short* __restrict__ W2b,
    const float* __restrict__ cb, float* __restrict__ part) {
    const int b   = blockIdx.y;
    const int ts  = blockIdx.x;
    const int t0  = ts * TC;
    const int tid = threadIdx.x;
    const int lane = tid & 63;
    const int w   = tid >> 6;            // 0..3 (o-block)
    const int g   = lane >> 4, li = lane & 15;

    // union: phase 1 uses first 4KB as Xb[32][64]; phase 2 uses 8KB as
    // Hl[32][128]. Barriers separate the lifetimes.
    __shared__ __align__(16) unsigned short LDS[32 * 128];
    unsigned short* Xb = LDS;
    unsigned short* Hl = LDS;

    const unsigned short* xtb = xt + (size_t)b * TP_ * C_;

    // ---------------- phase 1 ----------------
    f32x4 hacc[2][2];
    #pragma unroll
    for (int mi = 0; mi < 2; ++mi)
        #pragma unroll
        for (int ni = 0; ni < 2; ++ni)
            hacc[mi][ni] = (f32x4){0.f, 0.f, 0.f, 0.f};

    // staging: thread -> (t = tid>>3, slot s = tid&7), 1 short8 per chunk
    const int st_t = tid >> 3, st_s = tid & 7;
    short8 xs = *reinterpret_cast<const short8*>(
        xtb + (size_t)(t0 + st_t) * C_ + st_s * 8);

    // W1 A-row base (li -> 16 o-rows; g covers one 64B line per row)
    const unsigned short* arow0 = W1b + (size_t)(w * 32 + li) * C_ + g * 8;
    const unsigned short* arow1 = W1b + (size_t)(w * 32 + 16 + li) * C_ + g * 8;

    for (int kc = 0; kc < C_; kc += CH) {
        __syncthreads();   // prior-iter Xb reads complete
        *reinterpret_cast<short8*>(
            &Xb[st_t * 64 + ((st_s ^ (st_t & 7)) << 3)]) = xs;
        if (kc + CH < C_) {
            xs = *reinterpret_cast<const short8*>(
                xtb + (size_t)(t0 + st_t) * C_ + kc + CH + st_s * 8);
        }
        __syncthreads();
        #pragma unroll
        for (int ks = 0; ks < 2; ++ks) {
            short8 a0 = *reinterpret_cast<const short8*>(arow0 + kc + ks * 32);
            short8 a1 = *reinterpret_cast<const short8*>(arow1 + kc + ks * 32);
            short8 b0, b1;
            {
                int t = li;
                b0 = *reinterpret_cast<const short8*>(
                    &Xb[t * 64 + (((ks * 4 + g) ^ (t & 7)) << 3)]);
                t = 16 + li;
                b1 = *reinterpret_cast<const short8*>(
                    &Xb[t * 64 + (((ks * 4 + g) ^ (t & 7)) << 3)]);
            }
            hacc[0][0] = __builtin_amdgcn_mfma_f32_16x16x32_bf16(a0, b0, hacc[0][0], 0, 0, 0);
            hacc[0][1] = __builtin_amdgcn_mfma_f32_16x16x32_bf16(a0, b1, hacc[0][1], 0, 0, 0);
            hacc[1][0] = __builtin_amdgcn_mfma_f32_16x16x32_bf16(a1, b0, hacc[1][0], 0, 0, 0);
            hacc[1][1] = __builtin_amdgcn_mfma_f32_16x16x32_bf16(a1, b1, hacc[1][1], 0, 0, 0);
        }
    }

    // epilogue: +cb, relu, bf16 -> Hl[t][o] (swizzled 8B writes)
    __syncthreads();   // last Xb reads done before overwriting (union!)
    #pragma unroll
    for (int mi = 0; mi < 2; ++mi) {
        const int ob = w * 32 + mi * 16 + g * 4;
        const float4 cbv = *reinterpret_cast<const float4*>(cb + (size_t)b * BOT_ + ob);
        const int so = ob >> 3, off = ob & 7;   // off = 0 or 4
        #pragma unroll
        for (int ni = 0; ni < 2; ++ni) {
            int t = ni * 16 + li;
            short4v pk;
            pk[0] = (short)f2bf(fmaxf(hacc[mi][ni][0] + cbv.x, 0.f));
            pk[1] = (short)f2bf(fmaxf(hacc[mi][ni][1] + cbv.y, 0.f));
            pk[2] = (short)f2bf(fmaxf(hacc[mi][ni][2] + cbv.z, 0.f));
            pk[3] = (short)f2bf(fmaxf(hacc[mi][ni][3] + cbv.w, 0.f));
            *reinterpret_cast<short4v*>(
                &Hl[t * 128 + ((so ^ (t & 7)) << 3) + off]) = pk;
        }
    }
    __syncthreads();

    // ---------------- phase 2: swapped MFMA, lane = c ----------------
    float* pbase = part + ((size_t)(b * NTS + ts) * 3) * C_;

    for (int it = 0; it < 24; ++it) {
        const int c = it * 64 + w * 16 + li;
        // B-frags: W2b row c (li -> 16 c-rows; g covers one 64B line/row)
        short8 bfr[4];
        #pragma unroll
        for (int ks = 0; ks < 4; ++ks)
            bfr[ks] = *reinterpret_cast<const short8*>(
                W2b + (size_t)c * BOT_ + ks * 32 + g * 8);
        // logits: D[t][c], t in regs (32), c = lane
        f32x4 lacc[2];
        lacc[0] = (f32x4){0.f, 0.f, 0.f, 0.f};
        lacc[1] = (f32x4){0.f, 0.f, 0.f, 0.f};
        #pragma unroll
        for (int ks = 0; ks < 4; ++ks) {
            #pragma unroll
            for (int ni = 0; ni < 2; ++ni) {
                int t = ni * 16 + li;
                short8 af = *reinterpret_cast<const short8*>(
                    &Hl[t * 128 + (((ks * 4 + g) ^ (t & 7)) << 3)]);
                lacc[ni] = __builtin_amdgcn_mfma_f32_16x16x32_bf16(af, bfr[ks], lacc[ni], 0, 0, 0);
            }
        }
        // max-free exp + in-register t-accumulation; x from xt (t-major)
        float Z = 0.f, S1 = 0.f, S2 = 0.f;
        #pragma unroll
        for (int ni = 0; ni < 2; ++ni)
            #pragma unroll
            for (int r = 0; r < 4; ++r) {
                int tl = ni * 16 + g * 4 + r;
                int t  = t0 + tl;
                float p = __expf(lacc[ni][r]);
                p = (t < T_) ? p : 0.f;
                float xx = bf2f(xtb[(size_t)t * C_ + c]);
                Z += p;
                S1 = fmaf(xx, p, S1);
                S2 = fmaf(xx * xx, p, S2);
            }
        // reduce across g (lanes ^16, ^32)
        Z  += __shfl_xor(Z, 16);  Z  += __shfl_xor(Z, 32);
        S1 += __shfl_xor(S1, 16); S1 += __shfl_xor(S1, 32);
        S2 += __shfl_xor(S2, 16); S2 += __shfl_xor(S2, 32);
        if (lane < 16) {
            pbase[c]          = Z;
            pbase[C_ + c]     = S1;
            pbase[2 * C_ + c] = S2;
        }
    }
}

// ---------------------------------------------------------------------------
// K4: fold the NTS t-chunk partials, finalize wmean/wsd.
// ---------------------------------------------------------------------------
__global__ __launch_bounds__(256) void reduce_kernel(
    const float* __restrict__ part, float* __restrict__ out) {
    const int c = blockIdx.x * 256 + threadIdx.x;
    const int b = blockIdx.y;
    float Z = 0.f, S1 = 0.f, S2 = 0.f;
    for (int ts = 0; ts < NTS; ++ts) {
        const float* pb = part + ((size_t)(b * NTS + ts) * 3) * C_ + c;
        Z  += pb[0];
        S1 += pb[C_];
        S2 += pb[2 * C_];
    }
    float wmean = S1 / Z;
    float wsd   = sqrtf(fmaxf(S2 / Z - wmean * wmean, EPS_));
    out[(size_t)b * (2 * C_) + c]      = wmean;
    out[(size_t)b * (2 * C_) + C_ + c] = wsd;
}

// ---------------------------------------------------------------------------
extern "C" void kernel_launch(void* const* d_in, const int* in_sizes, int n_in,
                              void* d_out, int out_size, void* d_ws, size_t ws_size,
                              hipStream_t stream) {
    const float* x  = (const float*)d_in[0];   // [B, C, T]
    const float* W1 = (const float*)d_in[1];   // [BOT, 3C]
    const float* b1 = (const float*)d_in[2];   // [BOT]
    const float* W2 = (const float*)d_in[3];   // [C, BOT]
    // b2 (d_in[4]) cancels in softmax over T
    float* out = (float*)d_out;                // [B, 2C]

    float* ws = (float*)d_ws;
    float* mean_s = ws;                                   // B*C
    float* std_s  = mean_s + (size_t)B_ * C_;             // B*C
    float* cb     = std_s  + (size_t)B_ * C_;             // B*BOT
    float* part   = cb + (size_t)B_ * BOT_;               // B*NTS*3*C (37.7MB)
    unsigned short* W1b = (unsigned short*)(part + (size_t)B_ * NTS * 3 * C_);
    unsigned short* W2b = W1b + (size_t)BOT_ * C_;        // C*BOT
    unsigned short* xt  = W2b + (size_t)C_ * BOT_;        // B*TP*C bf16 (192MB)

    stats_transpose<<<dim3(C_ / 64, B_), 256, 0, stream>>>(x, mean_s, std_s, xt);
    cvt_kernel<<<dim3((BOT_ * C_ + 255) / 256), 256, 0, stream>>>(W1, W2, W1b, W2b);
    cb_kernel<<<dim3(B_), 128, 0, stream>>>(W1, b1, mean_s, std_s, cb);
    fused_main<<<dim3(NTS, B_), 256, 0, stream>>>(xt, W1b, W2b, cb, part);
    reduce_kernel<<<dim3(C_ / 256, B_), 256, 0, stream>>>(part, out);
}

// Round 14
// 419.925 us; speedup vs baseline: 1.0212x; 1.0212x over previous
//
#include <hip/hip_runtime.h>
#include <hip/hip_bf16.h>
#include <math.h>
#include <float.h>

#define B_    32
#define C_    1536
#define T_    2000
#define TP_   2048  // padded T for xt
#define BOT_  128
#define EPS_  1e-4f

#define CH    64    // c-chunk, phase 1
#define TC    128   // t-chunk per block
#define NTS   16    // 2048/128

typedef __attribute__((ext_vector_type(8))) short short8;
typedef __attribute__((ext_vector_type(4))) short short4v;
typedef __attribute__((ext_vector_type(4))) float f32x4;

static __device__ __forceinline__ unsigned short f2bf(float f) {
    unsigned u = __float_as_uint(f);
    u += 0x7FFFu + ((u >> 16) & 1u);           // RTNE
    return (unsigned short)(u >> 16);
}
static __device__ __forceinline__ float bf2f(unsigned short u) {
    return __uint_as_float(((unsigned)u) << 16);
}

// ---------------------------------------------------------------------------
// K1: per-(b,c) mean/std over T (fp32 exact) AND bf16 transpose xt[b][t][c]
// (t zero-padded to 2048). LDS-tiled transpose: reads coalesced along t
// (4 x 256B per instr), stride-72 ushort tile (odd slot stride -> conflict-
// free b128 readback), writes coalesced along c (8 x 128B per instr).
// Block = (64-c panel, b); 32 t-tiles of 64.
// ---------------------------------------------------------------------------
__global__ __launch_bounds__(256) void stats_transpose(
    const float* __restrict__ x, float* __restrict__ mean_s, float* __restrict__ std_s,
    unsigned short* __restrict__ xt) {
    const int b = blockIdx.y, cb0 = blockIdx.x * 64;
    const int tid = threadIdx.x;
    const int crow = tid >> 4;       // 0..15 (base read row)
    const int t4   = tid & 15;       // float4 index along t

    __shared__ __align__(16) unsigned short Tl[64 * 72];   // [t][c], stride 72

    const float* xb = x + ((size_t)b * C_ + cb0) * T_;
    unsigned short* xo = xt + (size_t)b * TP_ * C_ + cb0;

    float s1[4] = {0.f, 0.f, 0.f, 0.f}, s2[4] = {0.f, 0.f, 0.f, 0.f};

    for (int tt = 0; tt < TP_; tt += 64) {
        __syncthreads();   // prior tile's Tl reads complete
        // read (coalesced along t) + convert + transposed LDS write
        const int tg = tt + t4 * 4;
        #pragma unroll
        for (int i = 0; i < 4; ++i) {
            const int c = crow + 16 * i;
            f32x4 v;
            if (tg < T_) {          // T%4==0 -> float4 fully valid
                v = *reinterpret_cast<const f32x4*>(xb + (size_t)c * T_ + tg);
            } else {
                v = (f32x4){0.f, 0.f, 0.f, 0.f};
            }
            s1[i] += (v[0] + v[1]) + (v[2] + v[3]);
            s2[i] = fmaf(v[0], v[0], fmaf(v[1], v[1],
                    fmaf(v[2], v[2], fmaf(v[3], v[3], s2[i]))));
            #pragma unroll
            for (int j = 0; j < 4; ++j)
                Tl[(t4 * 4 + j) * 72 + c] = f2bf(v[j]);
        }
        __syncthreads();
        // write out: 2 short8 per thread, coalesced along c
        #pragma unroll
        for (int jj = 0; jj < 2; ++jj) {
            int idx = tid + 256 * jj;            // 0..511
            int t = idx >> 3, c8 = idx & 7;
            short8 vv = *reinterpret_cast<const short8*>(&Tl[t * 72 + c8 * 8]);
            *reinterpret_cast<short8*>(xo + (size_t)(tt + t) * C_ + c8 * 8) = vv;
        }
    }

    // reduce stats across the 16-lane t4 groups (offsets 1,2,4,8)
    #pragma unroll
    for (int i = 0; i < 4; ++i) {
        #pragma unroll
        for (int off = 1; off < 16; off <<= 1) {
            s1[i] += __shfl_xor(s1[i], off);
            s2[i] += __shfl_xor(s2[i], off);
        }
    }
    if (t4 == 0) {
        #pragma unroll
        for (int i = 0; i < 4; ++i) {
            const int c = crow + 16 * i;
            float mean = s1[i] / (float)T_;
            float var  = (s2[i] - s1[i] * mean) / (float)(T_ - 1);
            mean_s[(size_t)b * C_ + cb0 + c] = mean;
            std_s[(size_t)b * C_ + cb0 + c]  = sqrtf(fmaxf(var, EPS_));
        }
    }
}

// ---------------------------------------------------------------------------
// K1b: convert W1[:, :C] and W2 to bf16.
// ---------------------------------------------------------------------------
__global__ __launch_bounds__(256) void cvt_kernel(
    const float* __restrict__ W1, const float* __restrict__ W2,
    unsigned short* __restrict__ W1b, unsigned short* __restrict__ W2b) {
    int idx = blockIdx.x * 256 + threadIdx.x;
    if (idx < BOT_ * C_) {
        int o = idx / C_, c = idx - o * C_;
        W1b[idx] = f2bf(W1[(size_t)o * (3 * C_) + c]);
        W2b[idx] = f2bf(W2[idx]);
    }
}

// ---------------------------------------------------------------------------
// K2: cb[b][o] = b1[o] + sum_c W1[o][C+c]*mean[b][c] + W1[o][2C+c]*std[b][c]
// ---------------------------------------------------------------------------
__global__ __launch_bounds__(128) void cb_kernel(
    const float* __restrict__ W1, const float* __restrict__ b1,
    const float* __restrict__ mean_s, const float* __restrict__ std_s,
    float* __restrict__ cb) {
    __shared__ float ml[C_];
    __shared__ float sl[C_];
    const int b = blockIdx.x;
    for (int c = threadIdx.x; c < C_; c += 128) {
        ml[c] = mean_s[(size_t)b * C_ + c];
        sl[c] = std_s[(size_t)b * C_ + c];
    }
    __syncthreads();
    const int o = threadIdx.x;
    const float* wm = W1 + (size_t)o * (3 * C_) + C_;
    const float* ws = wm + C_;
    float am0 = 0.f, am1 = 0.f, as0 = 0.f, as1 = 0.f;
    for (int c = 0; c < C_; c += 2) {
        am0 = fmaf(wm[c],     ml[c],     am0);
        am1 = fmaf(wm[c + 1], ml[c + 1], am1);
        as0 = fmaf(ws[c],     sl[c],     as0);
        as1 = fmaf(ws[c + 1], sl[c + 1], as1);
    }
    cb[(size_t)b * BOT_ + o] = b1[o] + (am0 + am1) + (as0 + as1);
}

// ---------------------------------------------------------------------------
// K3 (fused, TC=128, glds staging): per (b, 128-t chunk), 4 waves:
//  phase 1: 24 chunks of 64 c. Xb (128t x 64c bf16) staged via
//    __builtin_amdgcn_global_load_lds width=16: linear LDS dest +
//    pre-swizzled per-lane global source (m173 pattern). No VGPR hop.
//    W1b A-frags direct from L2; 16 MFMA/wave per k-step of 32.
//  epilogue: +cb, relu -> Hl[128t][128o] bf16 (union over Xb).
//  phase 2: swapped MFMA (A = Hl t-rows, B = W2 c-rows), lane=c, regs=t;
//    max-free exp (|L|<~3, b2 cancels); x for S1/S2 from xt (t-major,
//    L3-resident); 2-shfl reduce; partials to ws.
// LDS = 32 KB (union). Grid (16, 32) = 512 blocks.
// ---------------------------------------------------------------------------
typedef const __attribute__((address_space(1))) unsigned int* gas_ptr;
typedef __attribute__((address_space(3))) unsigned int* las_ptr;

__global__ __launch_bounds__(256) void fused_main(
    const unsigned short* __restrict__ xt,
    const unsigned short* __restrict__ W1b, const unsigned short* __restrict__ W2b,
    const float* __restrict__ cb, float* __restrict__ part) {
    const int b   = blockIdx.y;
    const int ts  = blockIdx.x;
    const int t0  = ts * TC;
    const int tid = threadIdx.x;
    const int lane = tid & 63;
    const int w   = tid >> 6;            // 0..3
    const int oh  = w >> 1, th = w & 1;  // o-half (64), t-half (64)
    const int g   = lane >> 4, li = lane & 15;

    // union: phase 1 uses first 16KB as Xb[128][64]; phase 2 uses all 32KB
    // as Hl[128][128]. Barriers separate the lifetimes.
    __shared__ __align__(16) unsigned short LDS[128 * 128];
    unsigned short* Xb = LDS;
    unsigned short* Hl = LDS;

    const unsigned short* xtb = xt + (size_t)b * TP_ * C_;

    // ---------------- phase 1 ----------------
    f32x4 hacc[4][4];
    #pragma unroll
    for (int mi = 0; mi < 4; ++mi)
        #pragma unroll
        for (int ni = 0; ni < 4; ++ni)
            hacc[mi][ni] = (f32x4){0.f, 0.f, 0.f, 0.f};

    // glds mapping: slot s = i*256 + tid; t = s>>3, sl = s&7;
    // source column block = (sl ^ (t&7))  (inverse of the read swizzle).
    // Per-thread global base (kc added per chunk):
    const unsigned short* gsrc[4];
    #pragma unroll
    for (int i = 0; i < 4; ++i) {
        int s = i * 256 + tid;
        int t = s >> 3, sl = s & 7;
        gsrc[i] = xtb + (size_t)(t0 + t) * C_ + ((sl ^ (t & 7)) * 8);
    }

    // W1 row base pointers (k walks by 32 per ks)
    const unsigned short* arow[4];
    #pragma unroll
    for (int mi = 0; mi < 4; ++mi)
        arow[mi] = W1b + (size_t)(oh * 64 + mi * 16 + li) * C_ + g * 8;

    for (int kc = 0; kc < C_; kc += CH) {
        __syncthreads();   // prior-iter Xb reads complete
        // stage chunk kc via global_load_lds (16B per lane, linear LDS dest)
        #pragma unroll
        for (int i = 0; i < 4; ++i) {
            las_ptr lp = (las_ptr)&Xb[(i * 256 + w * 64) * 8];
            __builtin_amdgcn_global_load_lds((gas_ptr)(gsrc[i] + kc), lp, 16, 0, 0);
        }
        __syncthreads();   // drains vmcnt -> Xb ready
        // 2 k-steps of 32; 16 MFMA each
        #pragma unroll
        for (int ks = 0; ks < 2; ++ks) {
            short8 a[4], bb4[4];
            #pragma unroll
            for (int mi = 0; mi < 4; ++mi)
                a[mi] = *reinterpret_cast<const short8*>(arow[mi] + kc + ks * 32);
            #pragma unroll
            for (int ni = 0; ni < 4; ++ni) {
                int t = th * 64 + ni * 16 + li;
                bb4[ni] = *reinterpret_cast<const short8*>(
                    &Xb[t * 64 + (((ks * 4 + g) ^ (t & 7)) << 3)]);
            }
            #pragma unroll
            for (int mi = 0; mi < 4; ++mi)
                #pragma unroll
                for (int ni = 0; ni < 4; ++ni)
                    hacc[mi][ni] = __builtin_amdgcn_mfma_f32_16x16x32_bf16(a[mi], bb4[ni], hacc[mi][ni], 0, 0, 0);
        }
    }

    // epilogue: +cb, relu, bf16 -> Hl[t][o] (swizzled 8B writes).
    __syncthreads();   // last Xb reads done before overwriting (union!)
    #pragma unroll
    for (int mi = 0; mi < 4; ++mi) {
        const int ob = oh * 64 + mi * 16 + g * 4;
        const float4 cbv = *reinterpret_cast<const float4*>(cb + (size_t)b * BOT_ + ob);
        const int so = ob >> 3, off = ob & 7;   // off = 0 or 4
        #pragma unroll
        for (int ni = 0; ni < 4; ++ni) {
            int t = th * 64 + ni * 16 + li;
            short4v pk;
            pk[0] = (short)f2bf(fmaxf(hacc[mi][ni][0] + cbv.x, 0.f));
            pk[1] = (short)f2bf(fmaxf(hacc[mi][ni][1] + cbv.y, 0.f));
            pk[2] = (short)f2bf(fmaxf(hacc[mi][ni][2] + cbv.z, 0.f));
            pk[3] = (short)f2bf(fmaxf(hacc[mi][ni][3] + cbv.w, 0.f));
            *reinterpret_cast<short4v*>(
                &Hl[t * 128 + ((so ^ (t & 7)) << 3) + off]) = pk;
        }
    }
    __syncthreads();

    // ---------------- phase 2: swapped MFMA, lane = c ----------------
    float* pbase = part + ((size_t)(b * NTS + ts) * 3) * C_;

    for (int ccb = 0; ccb < C_; ccb += 64) {
        const int c = ccb + w * 16 + li;
        // B-frags: W2b row c (k = o contiguous), L1/L2-hot
        short8 bfr[4];
        #pragma unroll
        for (int ks = 0; ks < 4; ++ks)
            bfr[ks] = *reinterpret_cast<const short8*>(
                W2b + (size_t)c * BOT_ + ks * 32 + g * 8);

        float Z = 0.f, S1 = 0.f, S2 = 0.f;
        #pragma unroll
        for (int th2 = 0; th2 < 2; ++th2) {
            // logits for t-half th2: D[t][c], t in regs, c = lane
            f32x4 lacc[4];
            #pragma unroll
            for (int ni = 0; ni < 4; ++ni) lacc[ni] = (f32x4){0.f, 0.f, 0.f, 0.f};
            #pragma unroll
            for (int ks = 0; ks < 4; ++ks) {
                short8 af[4];
                #pragma unroll
                for (int ni = 0; ni < 4; ++ni) {
                    int t = th2 * 64 + ni * 16 + li;
                    af[ni] = *reinterpret_cast<const short8*>(
                        &Hl[t * 128 + (((ks * 4 + g) ^ (t & 7)) << 3)]);
                }
                #pragma unroll
                for (int ni = 0; ni < 4; ++ni)
                    lacc[ni] = __builtin_amdgcn_mfma_f32_16x16x32_bf16(af[ni], bfr[ks], lacc[ni], 0, 0, 0);
            }
            // max-free exp + in-register t-accumulation; x from xt (t-major)
            #pragma unroll
            for (int ni = 0; ni < 4; ++ni)
                #pragma unroll
                for (int r = 0; r < 4; ++r) {
                    int tl = th2 * 64 + ni * 16 + g * 4 + r;
                    int t  = t0 + tl;
                    float p = __expf(lacc[ni][r]);
                    p = (t < T_) ? p : 0.f;
                    float xx = bf2f(xtb[(size_t)t * C_ + c]);
                    Z += p;
                    S1 = fmaf(xx, p, S1);
                    S2 = fmaf(xx * xx, p, S2);
                }
        }
        // reduce across g (lanes ^16, ^32)
        Z  += __shfl_xor(Z, 16);  Z  += __shfl_xor(Z, 32);
        S1 += __shfl_xor(S1, 16); S1 += __shfl_xor(S1, 32);
        S2 += __shfl_xor(S2, 16); S2 += __shfl_xor(S2, 32);
        if (lane < 16) {
            pbase[c]          = Z;
            pbase[C_ + c]     = S1;
            pbase[2 * C_ + c] = S2;
        }
    }
}

// ---------------------------------------------------------------------------
// K4: fold the NTS t-chunk partials, finalize wmean/wsd.
// ---------------------------------------------------------------------------
__global__ __launch_bounds__(256) void reduce_kernel(
    const float* __restrict__ part, float* __restrict__ out) {
    const int c = blockIdx.x * 256 + threadIdx.x;
    const int b = blockIdx.y;
    float Z = 0.f, S1 = 0.f, S2 = 0.f;
    for (int ts = 0; ts < NTS; ++ts) {
        const float* pb = part + ((size_t)(b * NTS + ts) * 3) * C_ + c;
        Z  += pb[0];
        S1 += pb[C_];
        S2 += pb[2 * C_];
    }
    float wmean = S1 / Z;
    float wsd   = sqrtf(fmaxf(S2 / Z - wmean * wmean, EPS_));
    out[(size_t)b * (2 * C_) + c]      = wmean;
    out[(size_t)b * (2 * C_) + C_ + c] = wsd;
}

// ---------------------------------------------------------------------------
extern "C" void kernel_launch(void* const* d_in, const int* in_sizes, int n_in,
                              void* d_out, int out_size, void* d_ws, size_t ws_size,
                              hipStream_t stream) {
    const float* x  = (const float*)d_in[0];   // [B, C, T]
    const float* W1 = (const float*)d_in[1];   // [BOT, 3C]
    const float* b1 = (const float*)d_in[2];   // [BOT]
    const float* W2 = (const float*)d_in[3];   // [C, BOT]
    // b2 (d_in[4]) cancels in softmax over T
    float* out = (float*)d_out;                // [B, 2C]

    float* ws = (float*)d_ws;
    float* mean_s = ws;                                   // B*C
    float* std_s  = mean_s + (size_t)B_ * C_;             // B*C
    float* cb     = std_s  + (size_t)B_ * C_;             // B*BOT
    float* part   = cb + (size_t)B_ * BOT_;               // B*NTS*3*C (9.4MB)
    unsigned short* W1b = (unsigned short*)(part + (size_t)B_ * NTS * 3 * C_);
    unsigned short* W2b = W1b + (size_t)BOT_ * C_;        // C*BOT
    unsigned short* xt  = W2b + (size_t)C_ * BOT_;        // B*TP*C bf16 (192MB)

    stats_transpose<<<dim3(C_ / 64, B_), 256, 0, stream>>>(x, mean_s, std_s, xt);
    cvt_kernel<<<dim3((BOT_ * C_ + 255) / 256), 256, 0, stream>>>(W1, W2, W1b, W2b);
    cb_kernel<<<dim3(B_), 128, 0, stream>>>(W1, b1, mean_s, std_s, cb);
    fused_main<<<dim3(NTS, B_), 256, 0, stream>>>(xt, W1b, W2b, cb, part);
    reduce_kernel<<<dim3(C_ / 256, B_), 256, 0, stream>>>(part, out);
}

// Round 15
// 358.769 us; speedup vs baseline: 1.1953x; 1.1705x over previous
//
#include <hip/hip_runtime.h>
#include <hip/hip_bf16.h>
#include <math.h>
#include <float.h>

#define B_    32
#define C_    1536
#define T_    2000
#define TP_   2048  // padded T for xt
#define BOT_  128
#define EPS_  1e-4f

#define CH    64    // c-chunk, phase 1
#define NCH   24    // C_/CH
#define TC    128   // t-chunk per block
#define NTS   16    // 2048/128

typedef __attribute__((ext_vector_type(8))) short short8;
typedef __attribute__((ext_vector_type(4))) short short4v;
typedef __attribute__((ext_vector_type(4))) float f32x4;

static __device__ __forceinline__ unsigned short f2bf(float f) {
    unsigned u = __float_as_uint(f);
    u += 0x7FFFu + ((u >> 16) & 1u);           // RTNE
    return (unsigned short)(u >> 16);
}
static __device__ __forceinline__ float bf2f(unsigned short u) {
    return __uint_as_float(((unsigned)u) << 16);
}

// ---------------------------------------------------------------------------
// K1: per-(b,c) mean/std over T (fp32 exact) AND bf16 transpose xt[b][t][c]
// (t zero-padded to 2048). LDS-tiled transpose, conflict-free both sides.
// ---------------------------------------------------------------------------
__global__ __launch_bounds__(256) void stats_transpose(
    const float* __restrict__ x, float* __restrict__ mean_s, float* __restrict__ std_s,
    unsigned short* __restrict__ xt) {
    const int b = blockIdx.y, cb0 = blockIdx.x * 64;
    const int tid = threadIdx.x;
    const int crow = tid >> 4;       // 0..15 (base read row)
    const int t4   = tid & 15;       // float4 index along t

    __shared__ __align__(16) unsigned short Tl[64 * 72];   // [t][c], stride 72

    const float* xb = x + ((size_t)b * C_ + cb0) * T_;
    unsigned short* xo = xt + (size_t)b * TP_ * C_ + cb0;

    float s1[4] = {0.f, 0.f, 0.f, 0.f}, s2[4] = {0.f, 0.f, 0.f, 0.f};

    for (int tt = 0; tt < TP_; tt += 64) {
        __syncthreads();   // prior tile's Tl reads complete
        const int tg = tt + t4 * 4;
        #pragma unroll
        for (int i = 0; i < 4; ++i) {
            const int c = crow + 16 * i;
            f32x4 v;
            if (tg < T_) {          // T%4==0 -> float4 fully valid
                v = *reinterpret_cast<const f32x4*>(xb + (size_t)c * T_ + tg);
            } else {
                v = (f32x4){0.f, 0.f, 0.f, 0.f};
            }
            s1[i] += (v[0] + v[1]) + (v[2] + v[3]);
            s2[i] = fmaf(v[0], v[0], fmaf(v[1], v[1],
                    fmaf(v[2], v[2], fmaf(v[3], v[3], s2[i]))));
            #pragma unroll
            for (int j = 0; j < 4; ++j)
                Tl[(t4 * 4 + j) * 72 + c] = f2bf(v[j]);
        }
        __syncthreads();
        #pragma unroll
        for (int jj = 0; jj < 2; ++jj) {
            int idx = tid + 256 * jj;            // 0..511
            int t = idx >> 3, c8 = idx & 7;
            short8 vv = *reinterpret_cast<const short8*>(&Tl[t * 72 + c8 * 8]);
            *reinterpret_cast<short8*>(xo + (size_t)(tt + t) * C_ + c8 * 8) = vv;
        }
    }

    #pragma unroll
    for (int i = 0; i < 4; ++i) {
        #pragma unroll
        for (int off = 1; off < 16; off <<= 1) {
            s1[i] += __shfl_xor(s1[i], off);
            s2[i] += __shfl_xor(s2[i], off);
        }
    }
    if (t4 == 0) {
        #pragma unroll
        for (int i = 0; i < 4; ++i) {
            const int c = crow + 16 * i;
            float mean = s1[i] / (float)T_;
            float var  = (s2[i] - s1[i] * mean) / (float)(T_ - 1);
            mean_s[(size_t)b * C_ + cb0 + c] = mean;
            std_s[(size_t)b * C_ + cb0 + c]  = sqrtf(fmaxf(var, EPS_));
        }
    }
}

// ---------------------------------------------------------------------------
// K1b: convert W1[:, :C] and W2 to bf16.
// ---------------------------------------------------------------------------
__global__ __launch_bounds__(256) void cvt_kernel(
    const float* __restrict__ W1, const float* __restrict__ W2,
    unsigned short* __restrict__ W1b, unsigned short* __restrict__ W2b) {
    int idx = blockIdx.x * 256 + threadIdx.x;
    if (idx < BOT_ * C_) {
        int o = idx / C_, c = idx - o * C_;
        W1b[idx] = f2bf(W1[(size_t)o * (3 * C_) + c]);
        W2b[idx] = f2bf(W2[idx]);
    }
}

// ---------------------------------------------------------------------------
// K2: cb[b][o] = b1[o] + sum_c W1[o][C+c]*mean[b][c] + W1[o][2C+c]*std[b][c]
// ---------------------------------------------------------------------------
__global__ __launch_bounds__(128) void cb_kernel(
    const float* __restrict__ W1, const float* __restrict__ b1,
    const float* __restrict__ mean_s, const float* __restrict__ std_s,
    float* __restrict__ cb) {
    __shared__ float ml[C_];
    __shared__ float sl[C_];
    const int b = blockIdx.x;
    for (int c = threadIdx.x; c < C_; c += 128) {
        ml[c] = mean_s[(size_t)b * C_ + c];
        sl[c] = std_s[(size_t)b * C_ + c];
    }
    __syncthreads();
    const int o = threadIdx.x;
    const float* wm = W1 + (size_t)o * (3 * C_) + C_;
    const float* ws = wm + C_;
    float am0 = 0.f, am1 = 0.f, as0 = 0.f, as1 = 0.f;
    for (int c = 0; c < C_; c += 2) {
        am0 = fmaf(wm[c],     ml[c],     am0);
        am1 = fmaf(wm[c + 1], ml[c + 1], am1);
        as0 = fmaf(ws[c],     sl[c],     as0);
        as1 = fmaf(ws[c + 1], sl[c + 1], as1);
    }
    cb[(size_t)b * BOT_ + o] = b1[o] + (am0 + am1) + (as0 + as1);
}

// ---------------------------------------------------------------------------
// K3 (fused, counted-vmcnt pipeline): per (b, 128-t chunk), 4 waves.
//  phase 1: BOTH W1-tile (128o x 64c) and X-tile (128t x 64c) staged via
//    global_load_lds (8 glds/thread/chunk), DOUBLE-BUFFERED. K-loop uses
//    raw s_barrier + counted `s_waitcnt vmcnt(8)` — loads for the next
//    chunk stay in flight across barriers (T3+T4). No vector loads inside
//    the loop (the in-order vmcnt retirement would force a drain).
//  epilogue: +cb, relu -> Hl[128t][128o] bf16 (union over buffers).
//  phase 2: swapped MFMA (A = Hl t-rows, B = W2 c-rows), lane=c, regs=t;
//    max-free exp (|L|<~3, b2 cancels); x from xt; 2-shfl reduce.
// LDS = 64 KB (2 x (16K X + 16K W); Hl 32K union). Grid (16,32) = 512.
// ---------------------------------------------------------------------------
typedef const __attribute__((address_space(1))) unsigned int* gas_ptr;
typedef __attribute__((address_space(3))) unsigned int* las_ptr;

__global__ __launch_bounds__(256) void fused_main(
    const unsigned short* __restrict__ xt,
    const unsigned short* __restrict__ W1b, const unsigned short* __restrict__ W2b,
    const float* __restrict__ cb, float* __restrict__ part) {
    const int b   = blockIdx.y;
    const int ts  = blockIdx.x;
    const int t0  = ts * TC;
    const int tid = threadIdx.x;
    const int lane = tid & 63;
    const int w   = tid >> 6;            // 0..3
    const int oh  = w >> 1, th = w & 1;  // o-half (64), t-half (64)
    const int g   = lane >> 4, li = lane & 15;

    // LDS: buf p at p*16384 ushorts: [X 8192][W 8192]. Hl = first 16384.
    __shared__ __align__(16) unsigned short LDS[4 * 8192];  // 64KB
    unsigned short* Hl = LDS;

    const unsigned short* xtb = xt + (size_t)b * TP_ * C_;

    // ---------------- phase 1 ----------------
    f32x4 hacc[4][4];
    #pragma unroll
    for (int mi = 0; mi < 4; ++mi)
        #pragma unroll
        for (int ni = 0; ni < 4; ++ni)
            hacc[mi][ni] = (f32x4){0.f, 0.f, 0.f, 0.f};

    // glds source pointers. slot s = i*256+tid -> row r = s>>3, sl = s&7;
    // source column block pre-swizzled (inverse of read swizzle).
    const unsigned short* gX[4];
    const unsigned short* gW[4];
    #pragma unroll
    for (int i = 0; i < 4; ++i) {
        int s = i * 256 + tid;
        int r = s >> 3, sl = s & 7;
        gX[i] = xtb + (size_t)(t0 + r) * C_ + ((sl ^ (r & 7)) * 8);
        gW[i] = W1b + (size_t)r * C_ + ((sl ^ (r & 7)) * 8);
    }

    // stage chunk kc into buffer p (8 glds/thread, wave-uniform LDS bases)
    auto STAGE = [&](int p, int kc) {
        unsigned short* bx = LDS + p * 16384;
        unsigned short* bw = bx + 8192;
        #pragma unroll
        for (int i = 0; i < 4; ++i)
            __builtin_amdgcn_global_load_lds(
                (gas_ptr)(gX[i] + kc), (las_ptr)&bx[(i * 256 + w * 64) * 8], 16, 0, 0);
        #pragma unroll
        for (int i = 0; i < 4; ++i)
            __builtin_amdgcn_global_load_lds(
                (gas_ptr)(gW[i] + kc), (las_ptr)&bw[(i * 256 + w * 64) * 8], 16, 0, 0);
    };

    // compute one chunk from buffer p
    auto COMPUTE = [&](int p) {
        const unsigned short* bx = LDS + p * 16384;
        const unsigned short* bw = bx + 8192;
        #pragma unroll
        for (int ks = 0; ks < 2; ++ks) {
            short8 a[4], bb4[4];
            #pragma unroll
            for (int mi = 0; mi < 4; ++mi) {
                int o = oh * 64 + mi * 16 + li;
                a[mi] = *reinterpret_cast<const short8*>(
                    &bw[o * 64 + (((ks * 4 + g) ^ (o & 7)) << 3)]);
            }
            #pragma unroll
            for (int ni = 0; ni < 4; ++ni) {
                int t = th * 64 + ni * 16 + li;
                bb4[ni] = *reinterpret_cast<const short8*>(
                    &bx[t * 64 + (((ks * 4 + g) ^ (t & 7)) << 3)]);
            }
            #pragma unroll
            for (int mi = 0; mi < 4; ++mi)
                #pragma unroll
                for (int ni = 0; ni < 4; ++ni)
                    hacc[mi][ni] = __builtin_amdgcn_mfma_f32_16x16x32_bf16(a[mi], bb4[ni], hacc[mi][ni], 0, 0, 0);
        }
    };

    // prologue: two stages in flight
    STAGE(0, 0);
    STAGE(1, CH);

    // steady state: counted vmcnt — never drain to 0
    for (int k = 0; k < NCH - 1; ++k) {
        const int cur = k & 1;
        asm volatile("s_waitcnt vmcnt(8)" ::: "memory");   // chunk k ready
        __builtin_amdgcn_s_barrier();
        COMPUTE(cur);
        __builtin_amdgcn_s_barrier();                      // all waves done reading
        if (k + 2 < NCH) STAGE(cur, (k + 2) * CH);
    }
    // peeled last chunk: full drain
    asm volatile("s_waitcnt vmcnt(0)" ::: "memory");
    __builtin_amdgcn_s_barrier();
    COMPUTE((NCH - 1) & 1);

    // epilogue: +cb, relu, bf16 -> Hl[t][o] (swizzled 8B writes; union!)
    __syncthreads();
    #pragma unroll
    for (int mi = 0; mi < 4; ++mi) {
        const int ob = oh * 64 + mi * 16 + g * 4;
        const float4 cbv = *reinterpret_cast<const float4*>(cb + (size_t)b * BOT_ + ob);
        const int so = ob >> 3, off = ob & 7;   // off = 0 or 4
        #pragma unroll
        for (int ni = 0; ni < 4; ++ni) {
            int t = th * 64 + ni * 16 + li;
            short4v pk;
            pk[0] = (short)f2bf(fmaxf(hacc[mi][ni][0] + cbv.x, 0.f));
            pk[1] = (short)f2bf(fmaxf(hacc[mi][ni][1] + cbv.y, 0.f));
            pk[2] = (short)f2bf(fmaxf(hacc[mi][ni][2] + cbv.z, 0.f));
            pk[3] = (short)f2bf(fmaxf(hacc[mi][ni][3] + cbv.w, 0.f));
            *reinterpret_cast<short4v*>(
                &Hl[t * 128 + ((so ^ (t & 7)) << 3) + off]) = pk;
        }
    }
    __syncthreads();

    // ---------------- phase 2: swapped MFMA, lane = c ----------------
    float* pbase = part + ((size_t)(b * NTS + ts) * 3) * C_;

    for (int ccb = 0; ccb < C_; ccb += 64) {
        const int c = ccb + w * 16 + li;
        short8 bfr[4];
        #pragma unroll
        for (int ks = 0; ks < 4; ++ks)
            bfr[ks] = *reinterpret_cast<const short8*>(
                W2b + (size_t)c * BOT_ + ks * 32 + g * 8);

        float Z = 0.f, S1 = 0.f, S2 = 0.f;
        #pragma unroll
        for (int th2 = 0; th2 < 2; ++th2) {
            f32x4 lacc[4];
            #pragma unroll
            for (int ni = 0; ni < 4; ++ni) lacc[ni] = (f32x4){0.f, 0.f, 0.f, 0.f};
            #pragma unroll
            for (int ks = 0; ks < 4; ++ks) {
                short8 af[4];
                #pragma unroll
                for (int ni = 0; ni < 4; ++ni) {
                    int t = th2 * 64 + ni * 16 + li;
                    af[ni] = *reinterpret_cast<const short8*>(
                        &Hl[t * 128 + (((ks * 4 + g) ^ (t & 7)) << 3)]);
                }
                #pragma unroll
                for (int ni = 0; ni < 4; ++ni)
                    lacc[ni] = __builtin_amdgcn_mfma_f32_16x16x32_bf16(af[ni], bfr[ks], lacc[ni], 0, 0, 0);
            }
            #pragma unroll
            for (int ni = 0; ni < 4; ++ni)
                #pragma unroll
                for (int r = 0; r < 4; ++r) {
                    int tl = th2 * 64 + ni * 16 + g * 4 + r;
                    int t  = t0 + tl;
                    float p = __expf(lacc[ni][r]);
                    p = (t < T_) ? p : 0.f;
                    float xx = bf2f(xtb[(size_t)t * C_ + c]);
                    Z += p;
                    S1 = fmaf(xx, p, S1);
                    S2 = fmaf(xx * xx, p, S2);
                }
        }
        Z  += __shfl_xor(Z, 16);  Z  += __shfl_xor(Z, 32);
        S1 += __shfl_xor(S1, 16); S1 += __shfl_xor(S1, 32);
        S2 += __shfl_xor(S2, 16); S2 += __shfl_xor(S2, 32);
        if (lane < 16) {
            pbase[c]          = Z;
            pbase[C_ + c]     = S1;
            pbase[2 * C_ + c] = S2;
        }
    }
}

// ---------------------------------------------------------------------------
// K4: fold the NTS t-chunk partials, finalize wmean/wsd.
// ---------------------------------------------------------------------------
__global__ __launch_bounds__(256) void reduce_kernel(
    const float* __restrict__ part, float* __restrict__ out) {
    const int c = blockIdx.x * 256 + threadIdx.x;
    const int b = blockIdx.y;
    float Z = 0.f, S1 = 0.f, S2 = 0.f;
    for (int ts = 0; ts < NTS; ++ts) {
        const float* pb = part + ((size_t)(b * NTS + ts) * 3) * C_ + c;
        Z  += pb[0];
        S1 += pb[C_];
        S2 += pb[2 * C_];
    }
    float wmean = S1 / Z;
    float wsd   = sqrtf(fmaxf(S2 / Z - wmean * wmean, EPS_));
    out[(size_t)b * (2 * C_) + c]      = wmean;
    out[(size_t)b * (2 * C_) + C_ + c] = wsd;
}

// ---------------------------------------------------------------------------
extern "C" void kernel_launch(void* const* d_in, const int* in_sizes, int n_in,
                              void* d_out, int out_size, void* d_ws, size_t ws_size,
                              hipStream_t stream) {
    const float* x  = (const float*)d_in[0];   // [B, C, T]
    const float* W1 = (const float*)d_in[1];   // [BOT, 3C]
    const float* b1 = (const float*)d_in[2];   // [BOT]
    const float* W2 = (const float*)d_in[3];   // [C, BOT]
    // b2 (d_in[4]) cancels in softmax over T
    float* out = (float*)d_out;                // [B, 2C]

    float* ws = (float*)d_ws;
    float* mean_s = ws;                                   // B*C
    float* std_s  = mean_s + (size_t)B_ * C_;             // B*C
    float* cb     = std_s  + (size_t)B_ * C_;             // B*BOT
    float* part   = cb + (size_t)B_ * BOT_;               // B*NTS*3*C (9.4MB)
    unsigned short* W1b = (unsigned short*)(part + (size_t)B_ * NTS * 3 * C_);
    unsigned short* W2b = W1b + (size_t)BOT_ * C_;        // C*BOT
    unsigned short* xt  = W2b + (size_t)C_ * BOT_;        // B*TP*C bf16 (192MB)

    stats_transpose<<<dim3(C_ / 64, B_), 256, 0, stream>>>(x, mean_s, std_s, xt);
    cvt_kernel<<<dim3((BOT_ * C_ + 255) / 256), 256, 0, stream>>>(W1, W2, W1b, W2b);
    cb_kernel<<<dim3(B_), 128, 0, stream>>>(W1, b1, mean_s, std_s, cb);
    fused_main<<<dim3(NTS, B_), 256, 0, stream>>>(xt, W1b, W2b, cb, part);
    reduce_kernel<<<dim3(C_ / 256, B_), 256, 0, stream>>>(part, out);
}

// Round 16
// 322.220 us; speedup vs baseline: 1.3308x; 1.1134x over previous
//
#include <hip/hip_runtime.h>
#include <hip/hip_bf16.h>
#include <math.h>
#include <float.h>

#define B_    32
#define C_    1536
#define T_    2000
#define TP_   2048  // padded T for xt
#define BOT_  128
#define EPS_  1e-4f

#define CH    64    // c-chunk, phase 1
#define NCH   24    // C_/CH
#define TC    128   // t-chunk per block (fused)
#define NTS   16    // 2048/128
#define NT_ST 8     // t-chunks for stats kernel (2048/256)

typedef __attribute__((ext_vector_type(8))) short short8;
typedef __attribute__((ext_vector_type(4))) short short4v;
typedef __attribute__((ext_vector_type(4))) float f32x4;

static __device__ __forceinline__ unsigned short f2bf(float f) {
    unsigned u = __float_as_uint(f);
    u += 0x7FFFu + ((u >> 16) & 1u);           // RTNE
    return (unsigned short)(u >> 16);
}
static __device__ __forceinline__ float bf2f(unsigned short u) {
    return __uint_as_float(((unsigned)u) << 16);
}

// ---------------------------------------------------------------------------
// K1: bf16 transpose xt[b][t][c] (t zero-padded to 2048) + per-(b,c) partial
// sums s1/s2 over a 256-t chunk. Grid (C/64, 8 t-chunks, B) = 6144 blocks —
// TLP hides the per-tile barrier drains that serialized the old version.
// ---------------------------------------------------------------------------
__global__ __launch_bounds__(256) void stats_transpose(
    const float* __restrict__ x, float* __restrict__ spart,
    unsigned short* __restrict__ xt) {
    const int cb0 = blockIdx.x * 64;
    const int tc  = blockIdx.y;
    const int b   = blockIdx.z;
    const int tid = threadIdx.x;
    const int crow = tid >> 4;       // 0..15 (base read row)
    const int t4   = tid & 15;       // float4 index along t

    __shared__ __align__(16) unsigned short Tl[64 * 72];   // [t][c], stride 72

    const float* xb = x + ((size_t)b * C_ + cb0) * T_;
    unsigned short* xo = xt + (size_t)b * TP_ * C_ + cb0;

    float s1[4] = {0.f, 0.f, 0.f, 0.f}, s2[4] = {0.f, 0.f, 0.f, 0.f};

    const int tt0 = tc * 256;
    for (int tt = tt0; tt < tt0 + 256; tt += 64) {
        __syncthreads();   // prior tile's Tl reads complete
        const int tg = tt + t4 * 4;
        #pragma unroll
        for (int i = 0; i < 4; ++i) {
            const int c = crow + 16 * i;
            f32x4 v;
            if (tg < T_) {          // T%4==0 -> float4 fully valid
                v = *reinterpret_cast<const f32x4*>(xb + (size_t)c * T_ + tg);
            } else {
                v = (f32x4){0.f, 0.f, 0.f, 0.f};
            }
            s1[i] += (v[0] + v[1]) + (v[2] + v[3]);
            s2[i] = fmaf(v[0], v[0], fmaf(v[1], v[1],
                    fmaf(v[2], v[2], fmaf(v[3], v[3], s2[i]))));
            #pragma unroll
            for (int j = 0; j < 4; ++j)
                Tl[(t4 * 4 + j) * 72 + c] = f2bf(v[j]);
        }
        __syncthreads();
        #pragma unroll
        for (int jj = 0; jj < 2; ++jj) {
            int idx = tid + 256 * jj;            // 0..511
            int t = idx >> 3, c8 = idx & 7;
            short8 vv = *reinterpret_cast<const short8*>(&Tl[t * 72 + c8 * 8]);
            *reinterpret_cast<short8*>(xo + (size_t)(tt + t) * C_ + c8 * 8) = vv;
        }
    }

    // reduce partials across the 16-lane t4 groups
    #pragma unroll
    for (int i = 0; i < 4; ++i) {
        #pragma unroll
        for (int off = 1; off < 16; off <<= 1) {
            s1[i] += __shfl_xor(s1[i], off);
            s2[i] += __shfl_xor(s2[i], off);
        }
    }
    if (t4 == 0) {
        float* sp = spart + ((size_t)(b * NT_ST + tc) * 2) * C_ + cb0;
        #pragma unroll
        for (int i = 0; i < 4; ++i) {
            const int c = crow + 16 * i;
            sp[c]      = s1[i];
            sp[C_ + c] = s2[i];
        }
    }
}

// ---------------------------------------------------------------------------
// K1b: convert W1[:, :C] and W2 to bf16.
// ---------------------------------------------------------------------------
__global__ __launch_bounds__(256) void cvt_kernel(
    const float* __restrict__ W1, const float* __restrict__ W2,
    unsigned short* __restrict__ W1b, unsigned short* __restrict__ W2b) {
    int idx = blockIdx.x * 256 + threadIdx.x;
    if (idx < BOT_ * C_) {
        int o = idx / C_, c = idx - o * C_;
        W1b[idx] = f2bf(W1[(size_t)o * (3 * C_) + c]);
        W2b[idx] = f2bf(W2[idx]);
    }
}

// ---------------------------------------------------------------------------
// K2: fold stats partials -> mean/std (LDS), then
// cb[b][o] = b1[o] + sum_c W1[o][C+c]*mean[c] + W1[o][2C+c]*std[c].
// Coalesced: 16 threads cooperate per o-row (256B per load group),
// float4 LDS reads, 4-step shfl reduce. Block = b.
// ---------------------------------------------------------------------------
__global__ __launch_bounds__(256) void cb_kernel(
    const float* __restrict__ W1, const float* __restrict__ b1,
    const float* __restrict__ spart, float* __restrict__ cb) {
    __shared__ __align__(16) float ml[C_];
    __shared__ __align__(16) float sl[C_];
    const int b = blockIdx.x, tid = threadIdx.x;

    for (int c = tid; c < C_; c += 256) {
        float s1 = 0.f, s2 = 0.f;
        #pragma unroll
        for (int tc = 0; tc < NT_ST; ++tc) {
            const float* sp = spart + ((size_t)(b * NT_ST + tc) * 2) * C_ + c;
            s1 += sp[0];
            s2 += sp[C_];
        }
        float mean = s1 / (float)T_;
        float var  = (s2 - s1 * mean) / (float)(T_ - 1);
        ml[c] = mean;
        sl[c] = sqrtf(fmaxf(var, EPS_));
    }
    __syncthreads();

    const int grp = tid >> 4, j = tid & 15;
    #pragma unroll
    for (int p = 0; p < 8; ++p) {
        const int o = p * 16 + grp;
        const float* wm = W1 + (size_t)o * (3 * C_) + C_;
        const float* ws = wm + C_;
        float am = 0.f, as = 0.f;
        #pragma unroll 4
        for (int k = 0; k < 24; ++k) {
            const int c = k * 64 + j * 4;
            float4 wmv = *reinterpret_cast<const float4*>(wm + c);
            float4 wsv = *reinterpret_cast<const float4*>(ws + c);
            float4 mlv = *reinterpret_cast<const float4*>(&ml[c]);
            float4 slv = *reinterpret_cast<const float4*>(&sl[c]);
            am = fmaf(wmv.x, mlv.x, fmaf(wmv.y, mlv.y,
                 fmaf(wmv.z, mlv.z, fmaf(wmv.w, mlv.w, am))));
            as = fmaf(wsv.x, slv.x, fmaf(wsv.y, slv.y,
                 fmaf(wsv.z, slv.z, fmaf(wsv.w, slv.w, as))));
        }
        float v = am + as;
        v += __shfl_xor(v, 1); v += __shfl_xor(v, 2);
        v += __shfl_xor(v, 4); v += __shfl_xor(v, 8);
        if (j == 0) cb[(size_t)b * BOT_ + o] = b1[o] + v;
    }
}

// ---------------------------------------------------------------------------
// K3 (fused, counted-vmcnt pipeline) — unchanged from r15 (verified).
// ---------------------------------------------------------------------------
typedef const __attribute__((address_space(1))) unsigned int* gas_ptr;
typedef __attribute__((address_space(3))) unsigned int* las_ptr;

__global__ __launch_bounds__(256) void fused_main(
    const unsigned short* __restrict__ xt,
    const unsigned short* __restrict__ W1b, const unsigned short* __restrict__ W2b,
    const float* __restrict__ cb, float* __restrict__ part) {
    const int b   = blockIdx.y;
    const int ts  = blockIdx.x;
    const int t0  = ts * TC;
    const int tid = threadIdx.x;
    const int lane = tid & 63;
    const int w   = tid >> 6;            // 0..3
    const int oh  = w >> 1, th = w & 1;  // o-half (64), t-half (64)
    const int g   = lane >> 4, li = lane & 15;

    // LDS: buf p at p*16384 ushorts: [X 8192][W 8192]. Hl = first 16384.
    __shared__ __align__(16) unsigned short LDS[4 * 8192];  // 64KB
    unsigned short* Hl = LDS;

    const unsigned short* xtb = xt + (size_t)b * TP_ * C_;

    f32x4 hacc[4][4];
    #pragma unroll
    for (int mi = 0; mi < 4; ++mi)
        #pragma unroll
        for (int ni = 0; ni < 4; ++ni)
            hacc[mi][ni] = (f32x4){0.f, 0.f, 0.f, 0.f};

    const unsigned short* gX[4];
    const unsigned short* gW[4];
    #pragma unroll
    for (int i = 0; i < 4; ++i) {
        int s = i * 256 + tid;
        int r = s >> 3, sl = s & 7;
        gX[i] = xtb + (size_t)(t0 + r) * C_ + ((sl ^ (r & 7)) * 8);
        gW[i] = W1b + (size_t)r * C_ + ((sl ^ (r & 7)) * 8);
    }

    auto STAGE = [&](int p, int kc) {
        unsigned short* bx = LDS + p * 16384;
        unsigned short* bw = bx + 8192;
        #pragma unroll
        for (int i = 0; i < 4; ++i)
            __builtin_amdgcn_global_load_lds(
                (gas_ptr)(gX[i] + kc), (las_ptr)&bx[(i * 256 + w * 64) * 8], 16, 0, 0);
        #pragma unroll
        for (int i = 0; i < 4; ++i)
            __builtin_amdgcn_global_load_lds(
                (gas_ptr)(gW[i] + kc), (las_ptr)&bw[(i * 256 + w * 64) * 8], 16, 0, 0);
    };

    auto COMPUTE = [&](int p) {
        const unsigned short* bx = LDS + p * 16384;
        const unsigned short* bw = bx + 8192;
        #pragma unroll
        for (int ks = 0; ks < 2; ++ks) {
            short8 a[4], bb4[4];
            #pragma unroll
            for (int mi = 0; mi < 4; ++mi) {
                int o = oh * 64 + mi * 16 + li;
                a[mi] = *reinterpret_cast<const short8*>(
                    &bw[o * 64 + (((ks * 4 + g) ^ (o & 7)) << 3)]);
            }
            #pragma unroll
            for (int ni = 0; ni < 4; ++ni) {
                int t = th * 64 + ni * 16 + li;
                bb4[ni] = *reinterpret_cast<const short8*>(
                    &bx[t * 64 + (((ks * 4 + g) ^ (t & 7)) << 3)]);
            }
            #pragma unroll
            for (int mi = 0; mi < 4; ++mi)
                #pragma unroll
                for (int ni = 0; ni < 4; ++ni)
                    hacc[mi][ni] = __builtin_amdgcn_mfma_f32_16x16x32_bf16(a[mi], bb4[ni], hacc[mi][ni], 0, 0, 0);
        }
    };

    STAGE(0, 0);
    STAGE(1, CH);

    for (int k = 0; k < NCH - 1; ++k) {
        const int cur = k & 1;
        asm volatile("s_waitcnt vmcnt(8)" ::: "memory");   // chunk k ready
        __builtin_amdgcn_s_barrier();
        COMPUTE(cur);
        __builtin_amdgcn_s_barrier();                      // all waves done reading
        if (k + 2 < NCH) STAGE(cur, (k + 2) * CH);
    }
    asm volatile("s_waitcnt vmcnt(0)" ::: "memory");
    __builtin_amdgcn_s_barrier();
    COMPUTE((NCH - 1) & 1);

    // epilogue: +cb, relu, bf16 -> Hl[t][o] (swizzled 8B writes; union!)
    __syncthreads();
    #pragma unroll
    for (int mi = 0; mi < 4; ++mi) {
        const int ob = oh * 64 + mi * 16 + g * 4;
        const float4 cbv = *reinterpret_cast<const float4*>(cb + (size_t)b * BOT_ + ob);
        const int so = ob >> 3, off = ob & 7;   // off = 0 or 4
        #pragma unroll
        for (int ni = 0; ni < 4; ++ni) {
            int t = th * 64 + ni * 16 + li;
            short4v pk;
            pk[0] = (short)f2bf(fmaxf(hacc[mi][ni][0] + cbv.x, 0.f));
            pk[1] = (short)f2bf(fmaxf(hacc[mi][ni][1] + cbv.y, 0.f));
            pk[2] = (short)f2bf(fmaxf(hacc[mi][ni][2] + cbv.z, 0.f));
            pk[3] = (short)f2bf(fmaxf(hacc[mi][ni][3] + cbv.w, 0.f));
            *reinterpret_cast<short4v*>(
                &Hl[t * 128 + ((so ^ (t & 7)) << 3) + off]) = pk;
        }
    }
    __syncthreads();

    // ---------------- phase 2: swapped MFMA, lane = c ----------------
    float* pbase = part + ((size_t)(b * NTS + ts) * 3) * C_;

    for (int ccb = 0; ccb < C_; ccb += 64) {
        const int c = ccb + w * 16 + li;
        short8 bfr[4];
        #pragma unroll
        for (int ks = 0; ks < 4; ++ks)
            bfr[ks] = *reinterpret_cast<const short8*>(
                W2b + (size_t)c * BOT_ + ks * 32 + g * 8);

        float Z = 0.f, S1 = 0.f, S2 = 0.f;
        #pragma unroll
        for (int th2 = 0; th2 < 2; ++th2) {
            f32x4 lacc[4];
            #pragma unroll
            for (int ni = 0; ni < 4; ++ni) lacc[ni] = (f32x4){0.f, 0.f, 0.f, 0.f};
            #pragma unroll
            for (int ks = 0; ks < 4; ++ks) {
                short8 af[4];
                #pragma unroll
                for (int ni = 0; ni < 4; ++ni) {
                    int t = th2 * 64 + ni * 16 + li;
                    af[ni] = *reinterpret_cast<const short8*>(
                        &Hl[t * 128 + (((ks * 4 + g) ^ (t & 7)) << 3)]);
                }
                #pragma unroll
                for (int ni = 0; ni < 4; ++ni)
                    lacc[ni] = __builtin_amdgcn_mfma_f32_16x16x32_bf16(af[ni], bfr[ks], lacc[ni], 0, 0, 0);
            }
            #pragma unroll
            for (int ni = 0; ni < 4; ++ni)
                #pragma unroll
                for (int r = 0; r < 4; ++r) {
                    int tl = th2 * 64 + ni * 16 + g * 4 + r;
                    int t  = t0 + tl;
                    float p = __expf(lacc[ni][r]);
                    p = (t < T_) ? p : 0.f;
                    float xx = bf2f(xtb[(size_t)t * C_ + c]);
                    Z += p;
                    S1 = fmaf(xx, p, S1);
                    S2 = fmaf(xx * xx, p, S2);
                }
        }
        Z  += __shfl_xor(Z, 16);  Z  += __shfl_xor(Z, 32);
        S1 += __shfl_xor(S1, 16); S1 += __shfl_xor(S1, 32);
        S2 += __shfl_xor(S2, 16); S2 += __shfl_xor(S2, 32);
        if (lane < 16) {
            pbase[c]          = Z;
            pbase[C_ + c]     = S1;
            pbase[2 * C_ + c] = S2;
        }
    }
}

// ---------------------------------------------------------------------------
// K4: fold the NTS t-chunk partials, finalize wmean/wsd.
// ---------------------------------------------------------------------------
__global__ __launch_bounds__(256) void reduce_kernel(
    const float* __restrict__ part, float* __restrict__ out) {
    const int c = blockIdx.x * 256 + threadIdx.x;
    const int b = blockIdx.y;
    float Z = 0.f, S1 = 0.f, S2 = 0.f;
    for (int ts = 0; ts < NTS; ++ts) {
        const float* pb = part + ((size_t)(b * NTS + ts) * 3) * C_ + c;
        Z  += pb[0];
        S1 += pb[C_];
        S2 += pb[2 * C_];
    }
    float wmean = S1 / Z;
    float wsd   = sqrtf(fmaxf(S2 / Z - wmean * wmean, EPS_));
    out[(size_t)b * (2 * C_) + c]      = wmean;
    out[(size_t)b * (2 * C_) + C_ + c] = wsd;
}

// ---------------------------------------------------------------------------
extern "C" void kernel_launch(void* const* d_in, const int* in_sizes, int n_in,
                              void* d_out, int out_size, void* d_ws, size_t ws_size,
                              hipStream_t stream) {
    const float* x  = (const float*)d_in[0];   // [B, C, T]
    const float* W1 = (const float*)d_in[1];   // [BOT, 3C]
    const float* b1 = (const float*)d_in[2];   // [BOT]
    const float* W2 = (const float*)d_in[3];   // [C, BOT]
    // b2 (d_in[4]) cancels in softmax over T
    float* out = (float*)d_out;                // [B, 2C]

    float* ws = (float*)d_ws;
    float* cb     = ws;                                    // B*BOT
    float* spart  = cb + (size_t)B_ * BOT_;                // B*NT_ST*2*C (3.1MB)
    float* part   = spart + (size_t)B_ * NT_ST * 2 * C_;   // B*NTS*3*C (9.4MB)
    unsigned short* W1b = (unsigned short*)(part + (size_t)B_ * NTS * 3 * C_);
    unsigned short* W2b = W1b + (size_t)BOT_ * C_;         // C*BOT
    unsigned short* xt  = W2b + (size_t)C_ * BOT_;         // B*TP*C bf16 (192MB)

    stats_transpose<<<dim3(C_ / 64, NT_ST, B_), 256, 0, stream>>>(x, spart, xt);
    cvt_kernel<<<dim3((BOT_ * C_ + 255) / 256), 256, 0, stream>>>(W1, W2, W1b, W2b);
    cb_kernel<<<dim3(B_), 256, 0, stream>>>(W1, b1, spart, cb);
    fused_main<<<dim3(NTS, B_), 256, 0, stream>>>(xt, W1b, W2b, cb, part);
    reduce_kernel<<<dim3(C_ / 256, B_), 256, 0, stream>>>(part, out);
}

// Round 17
// 270.603 us; speedup vs baseline: 1.5847x; 1.1907x over previous
//
#include <hip/hip_runtime.h>
#include <hip/hip_bf16.h>
#include <math.h>
#include <float.h>

#define B_    32
#define C_    1536
#define T_    2000
#define TP_   2048  // padded T for xt
#define BOT_  128
#define EPS_  1e-4f

#define CH    64    // c-chunk, phase 1
#define NCH   24    // C_/CH
#define TC    128   // t-chunk per block (fused)
#define NTS   16    // 2048/128
#define NT_ST 8     // t-chunks for stats kernel (2048/256)

typedef __attribute__((ext_vector_type(8))) short short8;
typedef __attribute__((ext_vector_type(4))) short short4v;
typedef __attribute__((ext_vector_type(4))) float f32x4;

static __device__ __forceinline__ unsigned short f2bf(float f) {
    unsigned u = __float_as_uint(f);
    u += 0x7FFFu + ((u >> 16) & 1u);           // RTNE
    return (unsigned short)(u >> 16);
}
static __device__ __forceinline__ float bf2f(unsigned short u) {
    return __uint_as_float(((unsigned)u) << 16);
}

// ---------------------------------------------------------------------------
// K1: bf16 transpose xt[b][t][c] (t zero-padded to 2048) + per-(b,c) partial
// sums s1/s2 over a 256-t chunk. Grid (C/64, 8, B) = 6144 blocks.
// ---------------------------------------------------------------------------
__global__ __launch_bounds__(256) void stats_transpose(
    const float* __restrict__ x, float* __restrict__ spart,
    unsigned short* __restrict__ xt) {
    const int cb0 = blockIdx.x * 64;
    const int tc  = blockIdx.y;
    const int b   = blockIdx.z;
    const int tid = threadIdx.x;
    const int crow = tid >> 4;       // 0..15 (base read row)
    const int t4   = tid & 15;       // float4 index along t

    __shared__ __align__(16) unsigned short Tl[64 * 72];   // [t][c], stride 72

    const float* xb = x + ((size_t)b * C_ + cb0) * T_;
    unsigned short* xo = xt + (size_t)b * TP_ * C_ + cb0;

    float s1[4] = {0.f, 0.f, 0.f, 0.f}, s2[4] = {0.f, 0.f, 0.f, 0.f};

    const int tt0 = tc * 256;
    for (int tt = tt0; tt < tt0 + 256; tt += 64) {
        __syncthreads();   // prior tile's Tl reads complete
        const int tg = tt + t4 * 4;
        #pragma unroll
        for (int i = 0; i < 4; ++i) {
            const int c = crow + 16 * i;
            f32x4 v;
            if (tg < T_) {          // T%4==0 -> float4 fully valid
                v = *reinterpret_cast<const f32x4*>(xb + (size_t)c * T_ + tg);
            } else {
                v = (f32x4){0.f, 0.f, 0.f, 0.f};
            }
            s1[i] += (v[0] + v[1]) + (v[2] + v[3]);
            s2[i] = fmaf(v[0], v[0], fmaf(v[1], v[1],
                    fmaf(v[2], v[2], fmaf(v[3], v[3], s2[i]))));
            #pragma unroll
            for (int j = 0; j < 4; ++j)
                Tl[(t4 * 4 + j) * 72 + c] = f2bf(v[j]);
        }
        __syncthreads();
        #pragma unroll
        for (int jj = 0; jj < 2; ++jj) {
            int idx = tid + 256 * jj;            // 0..511
            int t = idx >> 3, c8 = idx & 7;
            short8 vv = *reinterpret_cast<const short8*>(&Tl[t * 72 + c8 * 8]);
            *reinterpret_cast<short8*>(xo + (size_t)(tt + t) * C_ + c8 * 8) = vv;
        }
    }

    #pragma unroll
    for (int i = 0; i < 4; ++i) {
        #pragma unroll
        for (int off = 1; off < 16; off <<= 1) {
            s1[i] += __shfl_xor(s1[i], off);
            s2[i] += __shfl_xor(s2[i], off);
        }
    }
    if (t4 == 0) {
        float* sp = spart + ((size_t)(b * NT_ST + tc) * 2) * C_ + cb0;
        #pragma unroll
        for (int i = 0; i < 4; ++i) {
            const int c = crow + 16 * i;
            sp[c]      = s1[i];
            sp[C_ + c] = s2[i];
        }
    }
}

// ---------------------------------------------------------------------------
// K1b: convert W1[:, :C] and W2 to bf16.
// ---------------------------------------------------------------------------
__global__ __launch_bounds__(256) void cvt_kernel(
    const float* __restrict__ W1, const float* __restrict__ W2,
    unsigned short* __restrict__ W1b, unsigned short* __restrict__ W2b) {
    int idx = blockIdx.x * 256 + threadIdx.x;
    if (idx < BOT_ * C_) {
        int o = idx / C_, c = idx - o * C_;
        W1b[idx] = f2bf(W1[(size_t)o * (3 * C_) + c]);
        W2b[idx] = f2bf(W2[idx]);
    }
}

// ---------------------------------------------------------------------------
// K2: fold stats partials -> mean/std (LDS), then
// cb[b][o] = b1[o] + sum_c W1[o][C+c]*mean[c] + W1[o][2C+c]*std[c].
// ---------------------------------------------------------------------------
__global__ __launch_bounds__(256) void cb_kernel(
    const float* __restrict__ W1, const float* __restrict__ b1,
    const float* __restrict__ spart, float* __restrict__ cb) {
    __shared__ __align__(16) float ml[C_];
    __shared__ __align__(16) float sl[C_];
    const int b = blockIdx.x, tid = threadIdx.x;

    for (int c = tid; c < C_; c += 256) {
        float s1 = 0.f, s2 = 0.f;
        #pragma unroll
        for (int tc = 0; tc < NT_ST; ++tc) {
            const float* sp = spart + ((size_t)(b * NT_ST + tc) * 2) * C_ + c;
            s1 += sp[0];
            s2 += sp[C_];
        }
        float mean = s1 / (float)T_;
        float var  = (s2 - s1 * mean) / (float)(T_ - 1);
        ml[c] = mean;
        sl[c] = sqrtf(fmaxf(var, EPS_));
    }
    __syncthreads();

    const int grp = tid >> 4, j = tid & 15;
    #pragma unroll
    for (int p = 0; p < 8; ++p) {
        const int o = p * 16 + grp;
        const float* wm = W1 + (size_t)o * (3 * C_) + C_;
        const float* ws = wm + C_;
        float am = 0.f, as = 0.f;
        #pragma unroll 4
        for (int k = 0; k < 24; ++k) {
            const int c = k * 64 + j * 4;
            float4 wmv = *reinterpret_cast<const float4*>(wm + c);
            float4 wsv = *reinterpret_cast<const float4*>(ws + c);
            float4 mlv = *reinterpret_cast<const float4*>(&ml[c]);
            float4 slv = *reinterpret_cast<const float4*>(&sl[c]);
            am = fmaf(wmv.x, mlv.x, fmaf(wmv.y, mlv.y,
                 fmaf(wmv.z, mlv.z, fmaf(wmv.w, mlv.w, am))));
            as = fmaf(wsv.x, slv.x, fmaf(wsv.y, slv.y,
                 fmaf(wsv.z, slv.z, fmaf(wsv.w, slv.w, as))));
        }
        float v = am + as;
        v += __shfl_xor(v, 1); v += __shfl_xor(v, 2);
        v += __shfl_xor(v, 4); v += __shfl_xor(v, 8);
        if (j == 0) cb[(size_t)b * BOT_ + o] = b1[o] + v;
    }
}

// ---------------------------------------------------------------------------
// K3 (fused, counted-vmcnt pipeline, 8 waves + setprio):
//  phase 1: W1-tile (128o x 64c) + X-tile (128t x 64c) staged via
//    global_load_lds (4 glds/thread/chunk), double-buffered; raw s_barrier
//    + counted `s_waitcnt vmcnt(4)` keeps next-chunk loads in flight
//    across barriers. Wave = (o-half x t-quarter); 16 MFMA/wave/chunk
//    wrapped in s_setprio(1).
//  epilogue: +cb, relu -> Hl[128t][128o] bf16 (union over buffer 0).
//  phase 2: swapped MFMA (A = Hl t-rows, B = W2 c-rows), lane=c, regs=t;
//    128 c per iter (12 iters); max-free exp (|L|<~3, b2 cancels); x from
//    xt; 2-shfl reduce. 16 waves/CU = 4/SIMD.
// ---------------------------------------------------------------------------
typedef const __attribute__((address_space(1))) unsigned int* gas_ptr;
typedef __attribute__((address_space(3))) unsigned int* las_ptr;

__global__ __launch_bounds__(512) void fused_main(
    const unsigned short* __restrict__ xt,
    const unsigned short* __restrict__ W1b, const unsigned short* __restrict__ W2b,
    const float* __restrict__ cb, float* __restrict__ part) {
    const int b   = blockIdx.y;
    const int ts  = blockIdx.x;
    const int t0  = ts * TC;
    const int tid = threadIdx.x;
    const int lane = tid & 63;
    const int w   = tid >> 6;            // 0..7
    const int oh  = w >> 2, th = w & 3;  // o-half (64), t-quarter (32)
    const int g   = lane >> 4, li = lane & 15;

    // LDS: buf p at p*16384 ushorts: [X 8192][W 8192]. Hl = first 16384.
    __shared__ __align__(16) unsigned short LDS[4 * 8192];  // 64KB
    unsigned short* Hl = LDS;

    const unsigned short* xtb = xt + (size_t)b * TP_ * C_;

    // ---------------- phase 1 ----------------
    f32x4 hacc[4][2];
    #pragma unroll
    for (int mi = 0; mi < 4; ++mi)
        #pragma unroll
        for (int ni = 0; ni < 2; ++ni)
            hacc[mi][ni] = (f32x4){0.f, 0.f, 0.f, 0.f};

    // glds sources: slot s = i*512+tid -> row r = s>>3, sl = s&7;
    // source column block pre-swizzled (inverse of read swizzle).
    const unsigned short* gX[2];
    const unsigned short* gW[2];
    #pragma unroll
    for (int i = 0; i < 2; ++i) {
        int s = i * 512 + tid;
        int r = s >> 3, sl = s & 7;
        gX[i] = xtb + (size_t)(t0 + r) * C_ + ((sl ^ (r & 7)) * 8);
        gW[i] = W1b + (size_t)r * C_ + ((sl ^ (r & 7)) * 8);
    }

    auto STAGE = [&](int p, int kc) {
        unsigned short* bx = LDS + p * 16384;
        unsigned short* bw = bx + 8192;
        #pragma unroll
        for (int i = 0; i < 2; ++i)
            __builtin_amdgcn_global_load_lds(
                (gas_ptr)(gX[i] + kc), (las_ptr)&bx[(i * 512 + w * 64) * 8], 16, 0, 0);
        #pragma unroll
        for (int i = 0; i < 2; ++i)
            __builtin_amdgcn_global_load_lds(
                (gas_ptr)(gW[i] + kc), (las_ptr)&bw[(i * 512 + w * 64) * 8], 16, 0, 0);
    };

    auto COMPUTE = [&](int p) {
        const unsigned short* bx = LDS + p * 16384;
        const unsigned short* bw = bx + 8192;
        __builtin_amdgcn_s_setprio(1);
        #pragma unroll
        for (int ks = 0; ks < 2; ++ks) {
            short8 a[4], bb4[2];
            #pragma unroll
            for (int mi = 0; mi < 4; ++mi) {
                int o = oh * 64 + mi * 16 + li;
                a[mi] = *reinterpret_cast<const short8*>(
                    &bw[o * 64 + (((ks * 4 + g) ^ (o & 7)) << 3)]);
            }
            #pragma unroll
            for (int ni = 0; ni < 2; ++ni) {
                int t = th * 32 + ni * 16 + li;
                bb4[ni] = *reinterpret_cast<const short8*>(
                    &bx[t * 64 + (((ks * 4 + g) ^ (t & 7)) << 3)]);
            }
            #pragma unroll
            for (int mi = 0; mi < 4; ++mi)
                #pragma unroll
                for (int ni = 0; ni < 2; ++ni)
                    hacc[mi][ni] = __builtin_amdgcn_mfma_f32_16x16x32_bf16(a[mi], bb4[ni], hacc[mi][ni], 0, 0, 0);
        }
        __builtin_amdgcn_s_setprio(0);
    };

    STAGE(0, 0);
    STAGE(1, CH);

    for (int k = 0; k < NCH - 1; ++k) {
        const int cur = k & 1;
        asm volatile("s_waitcnt vmcnt(4)" ::: "memory");   // chunk k ready
        __builtin_amdgcn_s_barrier();
        COMPUTE(cur);
        __builtin_amdgcn_s_barrier();                      // all waves done reading
        if (k + 2 < NCH) STAGE(cur, (k + 2) * CH);
    }
    asm volatile("s_waitcnt vmcnt(0)" ::: "memory");
    __builtin_amdgcn_s_barrier();
    COMPUTE((NCH - 1) & 1);

    // epilogue: +cb, relu, bf16 -> Hl[t][o] (swizzled 8B writes; union!)
    __syncthreads();
    #pragma unroll
    for (int mi = 0; mi < 4; ++mi) {
        const int ob = oh * 64 + mi * 16 + g * 4;
        const float4 cbv = *reinterpret_cast<const float4*>(cb + (size_t)b * BOT_ + ob);
        const int so = ob >> 3, off = ob & 7;   // off = 0 or 4
        #pragma unroll
        for (int ni = 0; ni < 2; ++ni) {
            int t = th * 32 + ni * 16 + li;
            short4v pk;
            pk[0] = (short)f2bf(fmaxf(hacc[mi][ni][0] + cbv.x, 0.f));
            pk[1] = (short)f2bf(fmaxf(hacc[mi][ni][1] + cbv.y, 0.f));
            pk[2] = (short)f2bf(fmaxf(hacc[mi][ni][2] + cbv.z, 0.f));
            pk[3] = (short)f2bf(fmaxf(hacc[mi][ni][3] + cbv.w, 0.f));
            *reinterpret_cast<short4v*>(
                &Hl[t * 128 + ((so ^ (t & 7)) << 3) + off]) = pk;
        }
    }
    __syncthreads();

    // ---------------- phase 2: swapped MFMA, lane = c ----------------
    float* pbase = part + ((size_t)(b * NTS + ts) * 3) * C_;

    for (int ccb = 0; ccb < C_; ccb += 128) {
        const int c = ccb + w * 16 + li;     // 128 c per iter across 8 waves
        short8 bfr[4];
        #pragma unroll
        for (int ks = 0; ks < 4; ++ks)
            bfr[ks] = *reinterpret_cast<const short8*>(
                W2b + (size_t)c * BOT_ + ks * 32 + g * 8);

        float Z = 0.f, S1 = 0.f, S2 = 0.f;
        #pragma unroll
        for (int th2 = 0; th2 < 2; ++th2) {
            f32x4 lacc[4];
            #pragma unroll
            for (int ni = 0; ni < 4; ++ni) lacc[ni] = (f32x4){0.f, 0.f, 0.f, 0.f};
            __builtin_amdgcn_s_setprio(1);
            #pragma unroll
            for (int ks = 0; ks < 4; ++ks) {
                short8 af[4];
                #pragma unroll
                for (int ni = 0; ni < 4; ++ni) {
                    int t = th2 * 64 + ni * 16 + li;
                    af[ni] = *reinterpret_cast<const short8*>(
                        &Hl[t * 128 + (((ks * 4 + g) ^ (t & 7)) << 3)]);
                }
                #pragma unroll
                for (int ni = 0; ni < 4; ++ni)
                    lacc[ni] = __builtin_amdgcn_mfma_f32_16x16x32_bf16(af[ni], bfr[ks], lacc[ni], 0, 0, 0);
            }
            __builtin_amdgcn_s_setprio(0);
            #pragma unroll
            for (int ni = 0; ni < 4; ++ni)
                #pragma unroll
                for (int r = 0; r < 4; ++r) {
                    int tl = th2 * 64 + ni * 16 + g * 4 + r;
                    int t  = t0 + tl;
                    float p = __expf(lacc[ni][r]);
                    p = (t < T_) ? p : 0.f;
                    float xx = bf2f(xtb[(size_t)t * C_ + c]);
                    Z += p;
                    S1 = fmaf(xx, p, S1);
                    S2 = fmaf(xx * xx, p, S2);
                }
        }
        Z  += __shfl_xor(Z, 16);  Z  += __shfl_xor(Z, 32);
        S1 += __shfl_xor(S1, 16); S1 += __shfl_xor(S1, 32);
        S2 += __shfl_xor(S2, 16); S2 += __shfl_xor(S2, 32);
        if (lane < 16) {
            pbase[c]          = Z;
            pbase[C_ + c]     = S1;
            pbase[2 * C_ + c] = S2;
        }
    }
}

// ---------------------------------------------------------------------------
// K4: fold the NTS t-chunk partials, finalize wmean/wsd.
// ---------------------------------------------------------------------------
__global__ __launch_bounds__(256) void reduce_kernel(
    const float* __restrict__ part, float* __restrict__ out) {
    const int c = blockIdx.x * 256 + threadIdx.x;
    const int b = blockIdx.y;
    float Z = 0.f, S1 = 0.f, S2 = 0.f;
    for (int ts = 0; ts < NTS; ++ts) {
        const float* pb = part + ((size_t)(b * NTS + ts) * 3) * C_ + c;
        Z  += pb[0];
        S1 += pb[C_];
        S2 += pb[2 * C_];
    }
    float wmean = S1 / Z;
    float wsd   = sqrtf(fmaxf(S2 / Z - wmean * wmean, EPS_));
    out[(size_t)b * (2 * C_) + c]      = wmean;
    out[(size_t)b * (2 * C_) + C_ + c] = wsd;
}

// ---------------------------------------------------------------------------
extern "C" void kernel_launch(void* const* d_in, const int* in_sizes, int n_in,
                              void* d_out, int out_size, void* d_ws, size_t ws_size,
                              hipStream_t stream) {
    const float* x  = (const float*)d_in[0];   // [B, C, T]
    const float* W1 = (const float*)d_in[1];   // [BOT, 3C]
    const float* b1 = (const float*)d_in[2];   // [BOT]
    const float* W2 = (const float*)d_in[3];   // [C, BOT]
    // b2 (d_in[4]) cancels in softmax over T
    float* out = (float*)d_out;                // [B, 2C]

    float* ws = (float*)d_ws;
    float* cb     = ws;                                    // B*BOT
    float* spart  = cb + (size_t)B_ * BOT_;                // B*NT_ST*2*C (3.1MB)
    float* part   = spart + (size_t)B_ * NT_ST * 2 * C_;   // B*NTS*3*C (9.4MB)
    unsigned short* W1b = (unsigned short*)(part + (size_t)B_ * NTS * 3 * C_);
    unsigned short* W2b = W1b + (size_t)BOT_ * C_;         // C*BOT
    unsigned short* xt  = W2b + (size_t)C_ * BOT_;         // B*TP*C bf16 (192MB)

    stats_transpose<<<dim3(C_ / 64, NT_ST, B_), 256, 0, stream>>>(x, spart, xt);
    cvt_kernel<<<dim3((BOT_ * C_ + 255) / 256), 256, 0, stream>>>(W1, W2, W1b, W2b);
    cb_kernel<<<dim3(B_), 256, 0, stream>>>(W1, b1, spart, cb);
    fused_main<<<dim3(NTS, B_), 512, 0, stream>>>(xt, W1b, W2b, cb, part);
    reduce_kernel<<<dim3(C_ / 256, B_), 256, 0, stream>>>(part, out);
}